// Round 1
// baseline (4845.409 us; speedup 1.0000x reference)
//
#include <hip/hip_runtime.h>

#define DEVINL static __device__ __forceinline__

namespace {

constexpr int NV = 100000;   // variables
constexpr int NC = 50000;    // constraints
constexpr int NK = 20000;    // cuts
constexpr int EVC = 800000;  // var-cons edges
constexpr int EVK = 200000;  // var-cut edges
constexpr int R_TOT = NC + NV + NK + NV;  // 270000 CSR rows (cons | var<-vc | cut | var<-vk)
constexpr int SCAN_CHUNK = 2048;
constexpr int SCAN_NB = (R_TOT + SCAN_CHUNK - 1) / SCAN_CHUNK;  // 132

DEVINL float rl(float v, int lane) {
  // uniform-lane broadcast -> SGPR, feeds v_fma as the scalar operand
  return __int_as_float(__builtin_amdgcn_readlane(__float_as_int(v), lane));
}

DEVINL float wave_sum(float v) {
#pragma unroll
  for (int off = 32; off > 0; off >>= 1) v += __shfl_xor(v, off, 64);
  return v;
}

DEVINL float sigmoid_f(float x) { return 1.0f / (1.0f + __expf(-x)); }

// ---------- fused 2-layer node MLP: OUT = relu(X@W1+B1)@W2+B2 ----------
// wave = 64 output channels (lane j holds W columns j in VGPRs), 4 nodes/wave
template <int DIN>
__global__ void __launch_bounds__(256) mlp2_node_k(
    const float* __restrict__ X, const float* __restrict__ W1,
    const float* __restrict__ B1, const float* __restrict__ W2,
    const float* __restrict__ B2, float* __restrict__ OUT, int N) {
  const int j = threadIdx.x & 63;
  const int n0 = blockIdx.x * 16 + (threadIdx.x >> 6) * 4;
  float w1c[DIN];
#pragma unroll
  for (int k = 0; k < DIN; ++k) w1c[k] = W1[k * 64 + j];
  float w2c[64];
#pragma unroll
  for (int k = 0; k < 64; ++k) w2c[k] = W2[k * 64 + j];
  const float b1 = B1[j], b2 = B2[j];

  float xr[4], acc[4];
#pragma unroll
  for (int i = 0; i < 4; ++i) {
    const int n = n0 + i;
    xr[i] = (j < DIN && n < N) ? X[n * DIN + j] : 0.0f;
    acc[i] = b1;
  }
#pragma unroll
  for (int k = 0; k < DIN; ++k) {
#pragma unroll
    for (int i = 0; i < 4; ++i) acc[i] = fmaf(rl(xr[i], k), w1c[k], acc[i]);
  }
  float hid[4];
#pragma unroll
  for (int i = 0; i < 4; ++i) { hid[i] = fmaxf(acc[i], 0.0f); acc[i] = b2; }
#pragma unroll
  for (int k = 0; k < 64; ++k) {
#pragma unroll
    for (int i = 0; i < 4; ++i) acc[i] = fmaf(rl(hid[i], k), w2c[k], acc[i]);
  }
#pragma unroll
  for (int i = 0; i < 4; ++i) {
    const int n = n0 + i;
    if (n < N) OUT[n * 64 + j] = acc[i];
  }
}

// ---------- single-layer GEMV, no bias/act: OUT = X@W (K=64) ----------
__global__ void __launch_bounds__(256) gemv64_k(
    const float* __restrict__ X, const float* __restrict__ W,
    float* __restrict__ OUT, int N) {
  const int j = threadIdx.x & 63;
  const int n0 = blockIdx.x * 16 + (threadIdx.x >> 6) * 4;
  float wc[64];
#pragma unroll
  for (int k = 0; k < 64; ++k) wc[k] = W[k * 64 + j];
  float xr[4], acc[4];
#pragma unroll
  for (int i = 0; i < 4; ++i) {
    const int n = n0 + i;
    xr[i] = (n < N) ? X[n * 64 + j] : 0.0f;
    acc[i] = 0.0f;
  }
#pragma unroll
  for (int k = 0; k < 64; ++k) {
#pragma unroll
    for (int i = 0; i < 4; ++i) acc[i] = fmaf(rl(xr[i], k), wc[k], acc[i]);
  }
#pragma unroll
  for (int i = 0; i < 4; ++i) {
    const int n = n0 + i;
    if (n < N) OUT[n * 64 + j] = acc[i];
  }
}

// ---------- K=128 GEMV over concat([X1,X2]): gate (sigmoid) / upd1 (relu) ----------
template <int ACT>  // 1 = relu, 2 = sigmoid
__global__ void __launch_bounds__(256) gemv128_k(
    const float* __restrict__ X1, const float* __restrict__ X2,
    const float* __restrict__ W, const float* __restrict__ B,
    float* __restrict__ OUT, int N) {
  const int j = threadIdx.x & 63;
  const int n0 = blockIdx.x * 16 + (threadIdx.x >> 6) * 4;
  float wc[128];
#pragma unroll
  for (int k = 0; k < 128; ++k) wc[k] = W[k * 64 + j];
  const float b = B[j];
  float x1r[4], x2r[4], acc[4];
#pragma unroll
  for (int i = 0; i < 4; ++i) {
    const int n = n0 + i;
    x1r[i] = (n < N) ? X1[n * 64 + j] : 0.0f;
    x2r[i] = (n < N) ? X2[n * 64 + j] : 0.0f;
    acc[i] = b;
  }
#pragma unroll
  for (int k = 0; k < 64; ++k) {
#pragma unroll
    for (int i = 0; i < 4; ++i) acc[i] = fmaf(rl(x1r[i], k), wc[k], acc[i]);
  }
#pragma unroll
  for (int k = 0; k < 64; ++k) {
#pragma unroll
    for (int i = 0; i < 4; ++i) acc[i] = fmaf(rl(x2r[i], k), wc[64 + k], acc[i]);
  }
#pragma unroll
  for (int i = 0; i < 4; ++i) {
    const int n = n0 + i;
    if (n < N) {
      float v = acc[i];
      if (ACT == 1) v = fmaxf(v, 0.0f);
      if (ACT == 2) v = sigmoid_f(v);
      OUT[n * 64 + j] = v;
    }
  }
}

// ---------- upd2 + gate-mix + LayerNorm (fused epilogue) ----------
__global__ void __launch_bounds__(256) upd2fin_k(
    const float* __restrict__ UH, const float* __restrict__ W2,
    const float* __restrict__ B2, const float* __restrict__ GATE,
    const float* __restrict__ NODE, const float* __restrict__ LNG,
    const float* __restrict__ LNB, float* __restrict__ OUT, int N) {
  const int j = threadIdx.x & 63;
  const int n0 = blockIdx.x * 16 + (threadIdx.x >> 6) * 4;
  float wc[64];
#pragma unroll
  for (int k = 0; k < 64; ++k) wc[k] = W2[k * 64 + j];
  const float b2 = B2[j], lg = LNG[j], lb = LNB[j];
  float ur[4], acc[4];
#pragma unroll
  for (int i = 0; i < 4; ++i) {
    const int n = n0 + i;
    ur[i] = (n < N) ? UH[n * 64 + j] : 0.0f;
    acc[i] = b2;
  }
#pragma unroll
  for (int k = 0; k < 64; ++k) {
#pragma unroll
    for (int i = 0; i < 4; ++i) acc[i] = fmaf(rl(ur[i], k), wc[k], acc[i]);
  }
#pragma unroll
  for (int i = 0; i < 4; ++i) {
    const int n = n0 + i;
    if (n < N) {  // wave-uniform branch: safe around shuffles
      const float g = GATE[n * 64 + j];
      const float nd = NODE[n * 64 + j];
      const float o = fmaf(g, acc[i] - nd, nd);  // g*upd + (1-g)*node
      const float s1 = wave_sum(o);
      const float s2 = wave_sum(o * o);
      const float m = s1 * (1.0f / 64.0f);
      const float var = s2 * (1.0f / 64.0f) - m * m;
      OUT[n * 64 + j] = (o - m) * rsqrtf(var + 1e-3f) * lg + lb;
    }
  }
}

// ---------- factorized edge weight: sigmoid(relu(pa[s]+pb[d]+ef@W1c+b1)@w2+b2) ----------
__global__ void __launch_bounds__(256) edgew_k(
    const int* __restrict__ S, const int* __restrict__ D,
    const float* __restrict__ EFX, const float* __restrict__ PA,
    const float* __restrict__ PB, const float* __restrict__ W1C,
    const float* __restrict__ B1, const float* __restrict__ W2,
    const float* __restrict__ B2, float* __restrict__ EW, int E) {
  const int j = threadIdx.x & 63;
  const int e = blockIdx.x * 4 + (threadIdx.x >> 6);
  if (e >= E) return;
  float wc[8];
#pragma unroll
  for (int i = 0; i < 8; ++i) wc[i] = W1C[i * 64 + j];
  const int s = S[e], d = D[e];
  float h = PA[s * 64 + j] + PB[d * 64 + j] + B1[j];
  const float efv = (j < 8) ? EFX[e * 8 + j] : 0.0f;
#pragma unroll
  for (int i = 0; i < 8; ++i) h = fmaf(rl(efv, i), wc[i], h);
  h = fmaxf(h, 0.0f);
  const float t = wave_sum(h * W2[j]);
  if (j == 0) EW[e] = sigmoid_f(t + B2[0]);
}

// ---------- CSR aggregation: agg[n] = sum(msg[nbr]*w) / max(sum w, 1) ----------
__global__ void __launch_bounds__(256) agg_k(
    const int* __restrict__ row_ptr, const int* __restrict__ nbr,
    const float* __restrict__ val, const float* __restrict__ MSG,
    float* __restrict__ AGG, int base, int N) {
  const int j = threadIdx.x & 63;
  const int n = blockIdx.x * 4 + (threadIdx.x >> 6);
  if (n >= N) return;
  const int s = row_ptr[base + n], e = row_ptr[base + n + 1];
  float acc = 0.0f, deg = 0.0f;
  for (int p = s; p < e; ++p) {
    const int nb = nbr[p];
    const float w = val[p];
    acc = fmaf(MSG[nb * 64 + j], w, acc);
    deg += w;
  }
  AGG[n * 64 + j] = acc / fmaxf(deg, 1.0f);
}

// ---------- CSR build: count, scan, fill ----------
__global__ void __launch_bounds__(256) count_k(
    const int* __restrict__ S, const int* __restrict__ D,
    int* __restrict__ counts, int baseD, int baseS, int E) {
  const int e = blockIdx.x * 256 + threadIdx.x;
  if (e >= E) return;
  atomicAdd(&counts[baseD + D[e]], 1);
  atomicAdd(&counts[baseS + S[e]], 1);
}

__global__ void __launch_bounds__(256) fill_k(
    const int* __restrict__ S, const int* __restrict__ D,
    const float* __restrict__ EW, int* __restrict__ cursor,
    int* __restrict__ nbr, float* __restrict__ val,
    int baseD, int baseS, int E) {
  const int e = blockIdx.x * 256 + threadIdx.x;
  if (e >= E) return;
  const int s = S[e], d = D[e];
  const float w = EW[e];
  int p = atomicAdd(&cursor[baseD + d], 1);
  nbr[p] = s;
  val[p] = w;
  p = atomicAdd(&cursor[baseS + s], 1);
  nbr[p] = d;
  val[p] = w;
}

__global__ void __launch_bounds__(256) scan1_k(const int* __restrict__ in,
                                               int* __restrict__ bsum) {
  __shared__ int sd[256];
  const int t = threadIdx.x;
  const int base = blockIdx.x * SCAN_CHUNK + t * 8;
  int s = 0;
#pragma unroll
  for (int i = 0; i < 8; ++i) {
    const int idx = base + i;
    s += (idx < R_TOT) ? in[idx] : 0;
  }
  sd[t] = s;
  __syncthreads();
  for (int off = 128; off > 0; off >>= 1) {
    if (t < off) sd[t] += sd[t + off];
    __syncthreads();
  }
  if (t == 0) bsum[blockIdx.x] = sd[0];
}

__global__ void __launch_bounds__(256) scan2_k(int* __restrict__ bsum,
                                               int* __restrict__ row_ptr) {
  __shared__ int sd[256];
  const int t = threadIdx.x;
  const int v = (t < SCAN_NB) ? bsum[t] : 0;
  sd[t] = v;
  __syncthreads();
  for (int off = 1; off < 256; off <<= 1) {
    const int add = (t >= off) ? sd[t - off] : 0;
    __syncthreads();
    sd[t] += add;
    __syncthreads();
  }
  if (t < SCAN_NB) bsum[t] = sd[t] - v;  // exclusive block offsets
  if (t == 255) row_ptr[R_TOT] = sd[255];
}

__global__ void __launch_bounds__(256) scan3_k(const int* __restrict__ in,
                                               const int* __restrict__ bsum,
                                               int* __restrict__ out) {
  __shared__ int sd[256];
  const int t = threadIdx.x;
  const int base = blockIdx.x * SCAN_CHUNK + t * 8;
  int loc[8];
  int s = 0;
#pragma unroll
  for (int i = 0; i < 8; ++i) {
    loc[i] = s;
    const int idx = base + i;
    s += (idx < R_TOT) ? in[idx] : 0;
  }
  sd[t] = s;
  __syncthreads();
  const int v = s;
  for (int off = 1; off < 256; off <<= 1) {
    const int add = (t >= off) ? sd[t - off] : 0;
    __syncthreads();
    sd[t] += add;
    __syncthreads();
  }
  const int off0 = bsum[blockIdx.x] + (sd[t] - v);
#pragma unroll
  for (int i = 0; i < 8; ++i) {
    const int idx = base + i;
    if (idx < R_TOT) out[idx] = off0 + loc[i];
  }
}

}  // namespace

extern "C" void kernel_launch(void* const* d_in, const int* in_sizes, int n_in,
                              void* d_out, int out_size, void* d_ws, size_t ws_size,
                              hipStream_t stream) {
  (void)in_sizes; (void)n_in; (void)out_size; (void)ws_size;

  // ---- inputs (setup_inputs dict order) ----
  const float* variable_features   = (const float*)d_in[0];
  const float* constraint_features = (const float*)d_in[1];
  const float* cut_features        = (const float*)d_in[2];
  const float* vc_ef = (const float*)d_in[3];
  const float* vk_ef = (const float*)d_in[4];
  const int* vc_edges = (const int*)d_in[5];
  const int* vk_edges = (const int*)d_in[6];
  const int *vc_s = vc_edges, *vc_d = vc_edges + EVC;
  const int *vk_s = vk_edges, *vk_d = vk_edges + EVK;
  const float* var_w1  = (const float*)d_in[7];
  const float* var_b1  = (const float*)d_in[8];
  const float* var_w2  = (const float*)d_in[9];
  const float* var_b2  = (const float*)d_in[10];
  const float* cons_w1 = (const float*)d_in[11];
  const float* cons_b1 = (const float*)d_in[12];
  const float* cons_w2 = (const float*)d_in[13];
  const float* cons_b2 = (const float*)d_in[14];
  const float* cut_w1  = (const float*)d_in[15];
  const float* cut_b1  = (const float*)d_in[16];
  const float* cut_w2  = (const float*)d_in[17];
  const float* cut_b2  = (const float*)d_in[18];
  const float* ewvc_w1 = (const float*)d_in[19];
  const float* ewvc_b1 = (const float*)d_in[20];
  const float* ewvc_w2 = (const float*)d_in[21];
  const float* ewvc_b2 = (const float*)d_in[22];
  const float* ewvk_w1 = (const float*)d_in[23];
  const float* ewvk_b1 = (const float*)d_in[24];
  const float* ewvk_w2 = (const float*)d_in[25];
  const float* ewvk_b2 = (const float*)d_in[26];
  const float* mp_msg_w1 = (const float*)d_in[27];
  const float* mp_msg_b1 = (const float*)d_in[28];
  const float* mp_msg_w2 = (const float*)d_in[29];
  const float* mp_msg_b2 = (const float*)d_in[30];
  const float* mp_gate_w = (const float*)d_in[31];
  const float* mp_gate_b = (const float*)d_in[32];
  const float* mp_upd_w1 = (const float*)d_in[33];
  const float* mp_upd_b1 = (const float*)d_in[34];
  const float* mp_upd_w2 = (const float*)d_in[35];
  const float* mp_upd_b2 = (const float*)d_in[36];
  const float* mp_ln_g   = (const float*)d_in[37];
  const float* mp_ln_b   = (const float*)d_in[38];

  // ---- workspace carve (~165 MB) ----
  char* wp = (char*)d_ws;
  auto take = [&](size_t nbytes) {
    char* p = wp;
    wp += (nbytes + 255) & ~(size_t)255;
    return p;
  };
  float* h_var  = (float*)take((size_t)NV * 64 * 4);
  float* h_cons = (float*)take((size_t)NC * 64 * 4);
  float* h_cut  = (float*)take((size_t)NK * 64 * 4);
  float* bufA = (float*)take((size_t)NV * 64 * 4);  // pa | msg
  float* bufB = (float*)take((size_t)NV * 64 * 4);  // pb | agg
  float* bufC = (float*)take((size_t)NV * 64 * 4);  // qa | gate
  float* bufD = (float*)take((size_t)NV * 64 * 4);  // qb | uh
  float* ew_vc = (float*)take((size_t)EVC * 4);
  float* ew_vk = (float*)take((size_t)EVK * 4);
  int* row_ptr = (int*)take((size_t)(R_TOT + 1) * 4);
  int* cursor  = (int*)take((size_t)R_TOT * 4);
  int* counts  = (int*)take((size_t)R_TOT * 4);
  int* bsum    = (int*)take(256 * 4);
  int* nbr     = (int*)take((size_t)(2 * EVC + 2 * EVK) * 4);
  float* val   = (float*)take((size_t)(2 * EVC + 2 * EVK) * 4);

  // ---- CSR counts + scan (edge weights filled in later) ----
  hipMemsetAsync(counts, 0, (size_t)R_TOT * 4, stream);
  count_k<<<(EVC + 255) / 256, 256, 0, stream>>>(vc_s, vc_d, counts, 0, NC, EVC);
  count_k<<<(EVK + 255) / 256, 256, 0, stream>>>(vk_s, vk_d, counts, NC + NV,
                                                 NC + NV + NK, EVK);
  scan1_k<<<SCAN_NB, 256, 0, stream>>>(counts, bsum);
  scan2_k<<<1, 256, 0, stream>>>(bsum, row_ptr);
  scan3_k<<<SCAN_NB, 256, 0, stream>>>(counts, bsum, row_ptr);

  // ---- embeddings ----
  mlp2_node_k<19><<<NV / 16, 256, 0, stream>>>(variable_features, var_w1, var_b1,
                                               var_w2, var_b2, h_var, NV);
  mlp2_node_k<5><<<NC / 16, 256, 0, stream>>>(constraint_features, cons_w1, cons_b1,
                                              cons_w2, cons_b2, h_cons, NC);
  mlp2_node_k<30><<<NK / 16, 256, 0, stream>>>(cut_features, cut_w1, cut_b1,
                                               cut_w2, cut_b2, h_cut, NK);

  // ---- edge weights: factorized per-node terms then per-edge combine ----
  gemv64_k<<<NV / 16, 256, 0, stream>>>(h_var, ewvc_w1, bufA, NV);              // pa
  gemv64_k<<<NC / 16, 256, 0, stream>>>(h_cons, ewvc_w1 + 64 * 64, bufB, NC);   // pb
  gemv64_k<<<NV / 16, 256, 0, stream>>>(h_var, ewvk_w1, bufC, NV);              // qa
  gemv64_k<<<NK / 16, 256, 0, stream>>>(h_cut, ewvk_w1 + 64 * 64, bufD, NK);    // qb
  edgew_k<<<EVC / 4, 256, 0, stream>>>(vc_s, vc_d, vc_ef, bufA, bufB,
                                       ewvc_w1 + 128 * 64, ewvc_b1, ewvc_w2,
                                       ewvc_b2, ew_vc, EVC);
  edgew_k<<<EVK / 4, 256, 0, stream>>>(vk_s, vk_d, vk_ef, bufC, bufD,
                                       ewvk_w1 + 128 * 64, ewvk_b1, ewvk_w2,
                                       ewvk_b2, ew_vk, EVK);

  // ---- CSR fill (stores edge weight as CSR value) ----
  hipMemcpyAsync(cursor, row_ptr, (size_t)R_TOT * 4, hipMemcpyDeviceToDevice, stream);
  fill_k<<<(EVC + 255) / 256, 256, 0, stream>>>(vc_s, vc_d, ew_vc, cursor, nbr,
                                                val, 0, NC, EVC);
  fill_k<<<(EVK + 255) / 256, 256, 0, stream>>>(vk_s, vk_d, ew_vk, cursor, nbr,
                                                val, NC + NV, NC + NV + NK, EVK);

  // ---- 15 message passes (16th only updates h_var -> dead, skipped) ----
  float* msgb = bufA;
  float* aggb = bufB;
  float* gateb = bufC;
  float* uhb = bufD;
  const float* neigh_t[4] = {h_var, h_cons, h_var, h_cut};
  float* node_t[4] = {h_cons, h_var, h_cut, h_var};
  const int Nn_t[4] = {NV, NC, NV, NK};
  const int Nd_t[4] = {NC, NV, NK, NV};
  const int base_t[4] = {0, NC, NC + NV, NC + NV + NK};

  for (int i = 0; i < 15; ++i) {
    const int d = i & 3;
    const float* neigh = neigh_t[d];
    float* node = node_t[d];
    const int Nn = Nn_t[d], Nd = Nd_t[d], base = base_t[d];

    const float* mW1 = mp_msg_w1 + (size_t)i * 4096;
    const float* mB1 = mp_msg_b1 + (size_t)i * 64;
    const float* mW2 = mp_msg_w2 + (size_t)i * 4096;
    const float* mB2 = mp_msg_b2 + (size_t)i * 64;
    const float* gW = mp_gate_w + (size_t)i * 8192;
    const float* gB = mp_gate_b + (size_t)i * 64;
    const float* uW1 = mp_upd_w1 + (size_t)i * 8192;
    const float* uB1 = mp_upd_b1 + (size_t)i * 64;
    const float* uW2 = mp_upd_w2 + (size_t)i * 4096;
    const float* uB2 = mp_upd_b2 + (size_t)i * 64;
    const float* lg = mp_ln_g + (size_t)i * 64;
    const float* lb = mp_ln_b + (size_t)i * 64;

    mlp2_node_k<64><<<(Nn + 15) / 16, 256, 0, stream>>>(neigh, mW1, mB1, mW2, mB2,
                                                        msgb, Nn);
    agg_k<<<(Nd + 3) / 4, 256, 0, stream>>>(row_ptr, nbr, val, msgb, aggb, base, Nd);
    gemv128_k<2><<<(Nd + 15) / 16, 256, 0, stream>>>(aggb, node, gW, gB, gateb, Nd);
    gemv128_k<1><<<(Nd + 15) / 16, 256, 0, stream>>>(aggb, node, uW1, uB1, uhb, Nd);
    float* outp = (i == 14) ? (float*)d_out : node;
    upd2fin_k<<<(Nd + 15) / 16, 256, 0, stream>>>(uhb, uW2, uB2, gateb, node, lg,
                                                  lb, outp, Nd);
  }
}